// Round 7
// baseline (148.501 us; speedup 1.0000x reference)
//
#include <hip/hip_runtime.h>

typedef _Float16 half8  __attribute__((ext_vector_type(8)));
typedef _Float16 half4v __attribute__((ext_vector_type(4)));
typedef _Float16 half2v __attribute__((ext_vector_type(2)));
typedef float    f32x4  __attribute__((ext_vector_type(4)));

#define N_VOX  262144
#define BATCH  4
#define NBOX   32
#define C3D_   64
#define C2D_   256
#define MIDC   128
#define OUTC   64
#define IH     96
#define IW     312
#define IHW    (IH*IW)          // 29952
#define EPSF   1e-5f
#define NTILES (N_VOX/64)       // 4096
#define GRIDX  768              // 3 blocks/CU * 256 CU

#define MFMA16(a,b,c) __builtin_amdgcn_mfma_f32_16x16x32_f16(a,b,c,0,0,0)

// ---------------------------------------------------------------------------
// prep: fp32 weights -> fp16 copies in workspace
// ---------------------------------------------------------------------------
__global__ __launch_bounds__(256) void prep_weights(
    const float* __restrict__ w_vt, const float* __restrict__ w_f,
    const float* __restrict__ w_it,
    _Float16* __restrict__ w_vt_h, _Float16* __restrict__ w_f_h,
    _Float16* __restrict__ w_it_h)
{
    int t = blockIdx.x * 256 + threadIdx.x;
    if (t < MIDC*C3D_) w_vt_h[t] = (_Float16)w_vt[t];
    if (t < OUTC*C2D_) w_f_h[t]  = (_Float16)w_f[t];
    if (t < MIDC*C2D_) w_it_h[t] = (_Float16)w_it[t];
}

// ---------------------------------------------------------------------------
// Kernel A: T = relu(BN(img @ w_it^T)), then J = T @ w_f[:,128:256]^T
// -> J[b][p][64] fp16.  (HBM-read-bound; unchanged from round 5.)
// ---------------------------------------------------------------------------
__global__ __launch_bounds__(256, 4) void img_transform(
    const float* __restrict__ img,        // [B][256][H*W]
    const _Float16* __restrict__ w_it_h,  // [128][256] fp16
    const _Float16* __restrict__ w_f_h,   // [64][256] fp16
    const float* __restrict__ b_it, const float* __restrict__ g_it,
    const float* __restrict__ be_it, const float* __restrict__ m_it,
    const float* __restrict__ v_it,
    _Float16* __restrict__ Jout)          // [B][H*W][64] fp16
{
    __shared__ __align__(16) _Float16 s_mem[64*136];

    const int p0   = blockIdx.x * 64;
    const int b    = blockIdx.y;
    const int tid  = threadIdx.x;
    const int lane = tid & 63;
    const int wv   = tid >> 6;
    const int r    = lane & 15;
    const int kh   = lane >> 4;

    f32x4 acc[4][2] = {};

    const int p  = tid & 63;
    const int cb = (tid >> 6) * 2;

    for (int kc = 0; kc < 4; ++kc) {
        #pragma unroll
        for (int i = 0; i < 8; ++i) {
            int c = cb + i*8;
            float x0 = img[(size_t)(b*C2D_ + kc*64 + c    )*IHW + p0 + p];
            float x1 = img[(size_t)(b*C2D_ + kc*64 + c + 1)*IHW + p0 + p];
            half2v h; h[0] = (_Float16)x0; h[1] = (_Float16)x1;
            *(half2v*)&s_mem[p*72 + c] = h;
        }
        half8 bw[2][2];
        #pragma unroll
        for (int nt = 0; nt < 2; ++nt)
            #pragma unroll
            for (int ks = 0; ks < 2; ++ks) {
                int o = wv*32 + nt*16 + r;
                bw[nt][ks] = *(const half8*)&w_it_h[o*C2D_ + kc*64 + ks*32 + kh*8];
            }
        __syncthreads();
        #pragma unroll
        for (int mt = 0; mt < 4; ++mt)
            #pragma unroll
            for (int ks = 0; ks < 2; ++ks) {
                half8 af = *(const half8*)&s_mem[(mt*16 + r)*72 + ks*32 + kh*8];
                acc[mt][0] = MFMA16(af, bw[0][ks], acc[mt][0]);
                acc[mt][1] = MFMA16(af, bw[1][ks], acc[mt][1]);
            }
        __syncthreads();
    }

    #pragma unroll
    for (int nt = 0; nt < 2; ++nt) {
        int o = wv*32 + nt*16 + r;
        float sa = g_it[o] * rsqrtf(v_it[o] + EPSF);
        float sb = (b_it[o] - m_it[o]) * sa + be_it[o];
        #pragma unroll
        for (int mt = 0; mt < 4; ++mt)
            #pragma unroll
            for (int rr = 0; rr < 4; ++rr) {
                int p2 = mt*16 + kh*4 + rr;
                float val = fmaxf(acc[mt][nt][rr]*sa + sb, 0.f);
                s_mem[p2*136 + o] = (_Float16)val;
            }
    }
    __syncthreads();

    {
        const int o2 = wv*16 + r;
        half8 bf2[4];
        #pragma unroll
        for (int ks = 0; ks < 4; ++ks)
            bf2[ks] = *(const half8*)&w_f_h[o2*C2D_ + 128 + ks*32 + kh*8];
        #pragma unroll
        for (int mt = 0; mt < 4; ++mt) {
            f32x4 a2 = {0.f,0.f,0.f,0.f};
            #pragma unroll
            for (int ks = 0; ks < 4; ++ks) {
                half8 af = *(const half8*)&s_mem[(mt*16 + r)*136 + ks*32 + kh*8];
                a2 = MFMA16(af, bf2[ks], a2);
            }
            #pragma unroll
            for (int rr = 0; rr < 4; ++rr) {
                int p2 = mt*16 + kh*4 + rr;
                Jout[(size_t)(b*IHW + p0 + p2)*OUTC + o2] = (_Float16)a2[rr];
            }
        }
    }
}

// ---------------------------------------------------------------------------
// meta + J-load-issue + box test for one tile (per-thread voxel vsv, quad q_)
// ---------------------------------------------------------------------------
__device__ __forceinline__ void prep_tile(
    const int4 cc, const int q_,
    const float* __restrict__ gtb, const int* __restrict__ gtc,
    const _Float16* __restrict__ Jimg,
    float* gw, half8 (*jreg)[2], float& w3)
{
    const int vb = cc.x;
    const float crx = cc.w * 0.05f;
    const float cry = cc.z * 0.05f - 40.0f;
    const float crz = cc.y * 0.1f  - 3.0f;
    const float px = (crx + 0.025f) * 10.f + 156.f;
    const float py = (cry + 0.025f) * 10.f + 48.f;
    const float nx = fminf(fmaxf(px / 312.f * 2.f - 1.f, -1.f), 1.f);
    const float ny = fminf(fmaxf(py / 96.f  * 2.f - 1.f, -1.f), 1.f);
    const float fx = ((nx + 1.f) * 312.f - 1.f) * 0.5f;
    const float fy = ((ny + 1.f) * 96.f  - 1.f) * 0.5f;
    const float x0f = floorf(fx), y0f = floorf(fy);
    const float wx1 = fx - x0f, wy1 = fy - y0f;
    const int x0 = (int)x0f, y0 = (int)y0f;
    #pragma unroll
    for (int c = 0; c < 4; ++c) {
        int xi = x0 + (c & 1), yi = y0 + (c >> 1);
        bool valid = (xi >= 0) && (xi < IW) && (yi >= 0) && (yi < IH);
        int xc = min(max(xi, 0), IW - 1);
        int yc = min(max(yi, 0), IH - 1);
        int ga = ((vb*IH + yc)*IW + xc) * OUTC;
        float wx = (c & 1) ? wx1 : 1.f - wx1;
        float wy = (c >> 1) ? wy1 : 1.f - wy1;
        gw[c] = valid ? wx * wy : 0.f;
        #pragma unroll
        for (int h = 0; h < 2; ++h)
            jreg[c][h] = *(const half8*)&Jimg[ga + (h*4 + q_)*8];
    }
    // box membership: 8 boxes per quad-lane, "last inside" = max index
    int lastm = -1;
    const float* gb = gtb + vb*(NBOX*7) + q_*56;
    #pragma unroll
    for (int mm = 0; mm < 8; ++mm) {
        float dx = gb[mm*7+3];
        bool in = (fabsf(crx - gb[mm*7+0]) < dx * 0.5f) &&
                  (fabsf(cry - gb[mm*7+1]) < gb[mm*7+4] * 0.5f) &&
                  (fabsf(crz - gb[mm*7+2]) < gb[mm*7+5] * 0.5f) &&
                  (dx > 0.f);
        if (in) lastm = q_*8 + mm;
    }
    lastm = max(lastm, __shfl_xor(lastm, 1));
    lastm = max(lastm, __shfl_xor(lastm, 2));
    int cls = gtc[vb*NBOX + max(lastm, 0)];
    w3 = (lastm < 0) ? 0.8f
       : ((cls == 0) ? 0.85f : ((cls == 1) ? 0.95f : 0.6f));
}

// ---------------------------------------------------------------------------
// Kernel B: persistent, 64 voxels/tile, ~5-6 tiles/block, software-pipelined.
// Raw barriers (lgkmcnt-only drain) keep prefetch loads in flight.
// ---------------------------------------------------------------------------
__global__ __launch_bounds__(256, 3) void voxel_fuse(
    const float* __restrict__ vf,     // [N][64]
    const int*   __restrict__ coords, // [N][4]
    const float* __restrict__ gtb,    // [B][32][7]
    const int*   __restrict__ gtc,    // [B][32]
    const _Float16* __restrict__ w_vt_h,  // [128][64]
    const float* __restrict__ b_vt, const float* __restrict__ g_vt,
    const float* __restrict__ be_vt, const float* __restrict__ m_vt,
    const float* __restrict__ v_vt,
    const _Float16* __restrict__ Jimg,    // [B][H*W][64]
    const _Float16* __restrict__ w_f_h,   // [64][256]
    const float* __restrict__ b_f, const float* __restrict__ g_f,
    const float* __restrict__ be_f, const float* __restrict__ m_f,
    const float* __restrict__ v_f,
    float* __restrict__ out)          // [N][64]
{
    __shared__ __align__(16) _Float16 s_vf[64*72];      // [v][k] pitch 72
    __shared__ __align__(16) _Float16 s_fused[64*136];  // [v][o] pitch 136
    __shared__ __align__(16) _Float16 s_j[64*72];       // [v][o] pitch 72
    __shared__ float s_w3d[64];

    const int tid  = threadIdx.x;
    const int lane = tid & 63;
    const int wv   = tid >> 6;
    const int r    = lane & 15;
    const int kh   = lane >> 4;
    const int vsv  = tid >> 2;
    const int q_   = tid & 3;

    // ---- loop-invariant prologue: weight fragments + BN constants ----
    half8 bvt[2][2];
    float savt[2], sbvt[2];
    #pragma unroll
    for (int nt = 0; nt < 2; ++nt) {
        int o = (2*wv + nt)*16 + r;
        #pragma unroll
        for (int ks = 0; ks < 2; ++ks)
            bvt[nt][ks] = *(const half8*)&w_vt_h[o*C3D_ + ks*32 + kh*8];
        savt[nt] = g_vt[o] * rsqrtf(v_vt[o] + EPSF);
        sbvt[nt] = (b_vt[o] - m_vt[o]) * savt[nt] + be_vt[o];
    }
    const int of = wv*16 + r;
    half8 bf1[4];
    #pragma unroll
    for (int ks = 0; ks < 4; ++ks)
        bf1[ks] = *(const half8*)&w_f_h[of*C2D_ + ks*32 + kh*8];
    const float saf = g_f[of] * rsqrtf(v_f[of] + EPSF);
    const float sbf = (b_f[of] - m_f[of]) * saf + be_f[of];

    // ---- tile prologue: tile t0 ----
    int t = blockIdx.x;
    int4 cc = ((const int4*)coords)[t*64 + vsv];
    float4 vfr[4];
    {
        const float4* src = (const float4*)(vf + (size_t)(t*64 + vsv)*C3D_ + q_*16);
        #pragma unroll
        for (int i = 0; i < 4; ++i) vfr[i] = src[i];
    }
    float gw[4]; half8 jreg[4][2]; float w3;
    prep_tile(cc, q_, gtb, gtc, Jimg, gw, jreg, w3);

    while (true) {
        int tn = t + GRIDX;
        const bool more = (tn < NTILES);
        if (!more) tn = t;

        // ---- A: prefetch next tile's vf + coords ----
        int4 cc_n = ((const int4*)coords)[tn*64 + vsv];
        float4 vfr_n[4];
        {
            const float4* src = (const float4*)(vf + (size_t)(tn*64 + vsv)*C3D_ + q_*16);
            #pragma unroll
            for (int i = 0; i < 4; ++i) vfr_n[i] = src[i];
        }

        // ---- B: stage vf(t) -> fp16 LDS; publish w3(t) ----
        #pragma unroll
        for (int i = 0; i < 4; ++i) {
            float4 x = vfr[i];
            half4v h;
            h[0] = (_Float16)x.x; h[1] = (_Float16)x.y;
            h[2] = (_Float16)x.z; h[3] = (_Float16)x.w;
            *(half4v*)&s_vf[vsv*72 + q_*16 + i*4] = h;
        }
        if (q_ == 0) s_w3d[vsv] = w3;
        asm volatile("s_waitcnt lgkmcnt(0)" ::: "memory");
        __builtin_amdgcn_s_barrier();
        asm volatile("" ::: "memory");

        // ---- C: phase 1a: vt = relu(BN(vf @ w_vt^T)) * w3d -> s_fused ----
        #pragma unroll
        for (int mt = 0; mt < 4; ++mt) {
            f32x4 a0 = {0.f,0.f,0.f,0.f}, a1 = {0.f,0.f,0.f,0.f};
            #pragma unroll
            for (int ks = 0; ks < 2; ++ks) {
                half8 af = *(const half8*)&s_vf[(mt*16 + r)*72 + ks*32 + kh*8];
                a0 = MFMA16(af, bvt[0][ks], a0);
                a1 = MFMA16(af, bvt[1][ks], a1);
            }
            #pragma unroll
            for (int rr = 0; rr < 4; ++rr) {
                int v = mt*16 + kh*4 + rr;
                float w3v = s_w3d[v];
                s_fused[v*136 + (2*wv+0)*16 + r] =
                    (_Float16)(fmaxf(a0[rr]*savt[0] + sbvt[0], 0.f) * w3v);
                s_fused[v*136 + (2*wv+1)*16 + r] =
                    (_Float16)(fmaxf(a1[rr]*savt[1] + sbvt[1], 0.f) * w3v);
            }
        }

        // ---- D: meta + J-issue + box for next tile (register-resident) ----
        float gw_n[4]; half8 jreg_n[4][2]; float w3_n;
        prep_tile(cc_n, q_, gtb, gtc, Jimg, gw_n, jreg_n, w3_n);

        // ---- E: gather combine (t): (1-w3d)*sum_c gw[c]*J_c -> s_j ----
        {
            float invw = 1.f - w3;
            #pragma unroll
            for (int h = 0; h < 2; ++h) {
                half8 res;
                #pragma unroll
                for (int i = 0; i < 8; ++i) {
                    float s = gw[0]*(float)jreg[0][h][i] + gw[1]*(float)jreg[1][h][i]
                            + gw[2]*(float)jreg[2][h][i] + gw[3]*(float)jreg[3][h][i];
                    res[i] = (_Float16)(s * invw);
                }
                *(half8*)&s_j[vsv*72 + (h*4 + q_)*8] = res;
            }
        }
        asm volatile("s_waitcnt lgkmcnt(0)" ::: "memory");
        __builtin_amdgcn_s_barrier();
        asm volatile("" ::: "memory");

        // ---- F: phase 2: out = relu(BN(fused @ Wf1^T + j)) ----
        {
            const int v0 = t * 64;
            #pragma unroll
            for (int mt = 0; mt < 4; ++mt) {
                f32x4 acc = {0.f,0.f,0.f,0.f};
                #pragma unroll
                for (int ks = 0; ks < 4; ++ks) {
                    half8 af = *(const half8*)&s_fused[(mt*16 + r)*136 + ks*32 + kh*8];
                    acc = MFMA16(af, bf1[ks], acc);
                }
                #pragma unroll
                for (int rr = 0; rr < 4; ++rr) {
                    int v = mt*16 + kh*4 + rr;
                    float jv = (float)s_j[v*72 + of];
                    out[(size_t)(v0 + v)*OUTC + of] =
                        fmaxf((acc[rr] + jv)*saf + sbf, 0.f);
                }
            }
        }

        // ---- rotate pipeline registers ----
        #pragma unroll
        for (int c = 0; c < 4; ++c) {
            gw[c] = gw_n[c];
            jreg[c][0] = jreg_n[c][0];
            jreg[c][1] = jreg_n[c][1];
        }
        w3 = w3_n;
        #pragma unroll
        for (int i = 0; i < 4; ++i) vfr[i] = vfr_n[i];

        if (!more) break;
        t = tn;
    }
}

// ---------------------------------------------------------------------------
extern "C" void kernel_launch(void* const* d_in, const int* in_sizes, int n_in,
                              void* d_out, int out_size, void* d_ws, size_t ws_size,
                              hipStream_t stream)
{
    const float* vf    = (const float*)d_in[0];
    const int*   vc    = (const int*)  d_in[1];
    const float* img   = (const float*)d_in[2];
    const float* gtb   = (const float*)d_in[3];
    const int*   gtc   = (const int*)  d_in[4];
    const float* w_vt  = (const float*)d_in[5];
    const float* b_vt  = (const float*)d_in[6];
    const float* g_vt  = (const float*)d_in[7];
    const float* be_vt = (const float*)d_in[8];
    const float* m_vt  = (const float*)d_in[9];
    const float* v_vt  = (const float*)d_in[10];
    const float* w_it  = (const float*)d_in[11];
    const float* b_it  = (const float*)d_in[12];
    const float* g_it  = (const float*)d_in[13];
    const float* be_it = (const float*)d_in[14];
    const float* m_it  = (const float*)d_in[15];
    const float* v_it  = (const float*)d_in[16];
    const float* w_f   = (const float*)d_in[17];
    const float* b_f   = (const float*)d_in[18];
    const float* g_f   = (const float*)d_in[19];
    const float* be_f  = (const float*)d_in[20];
    const float* m_f   = (const float*)d_in[21];
    const float* v_f   = (const float*)d_in[22];

    _Float16* ws_h   = (_Float16*)d_ws;
    _Float16* Jbuf   = ws_h;                              // B*IHW*64 halves
    _Float16* w_vt_h = ws_h + (size_t)BATCH*IHW*OUTC;
    _Float16* w_f_h  = w_vt_h + MIDC*C3D_;
    _Float16* w_it_h = w_f_h + OUTC*C2D_;
    float* outp = (float*)d_out;

    prep_weights<<<128, 256, 0, stream>>>(w_vt, w_f, w_it, w_vt_h, w_f_h, w_it_h);

    img_transform<<<dim3(IHW/64, BATCH), 256, 0, stream>>>(
        img, w_it_h, w_f_h, b_it, g_it, be_it, m_it, v_it, Jbuf);

    voxel_fuse<<<GRIDX, 256, 0, stream>>>(
        vf, vc, gtb, gtc, w_vt_h, b_vt, g_vt, be_vt, m_vt, v_vt,
        Jbuf, w_f_h, b_f, g_f, be_f, m_f, v_f, outp);
}

// Round 8
// 84.742 us; speedup vs baseline: 1.7524x; 1.7524x over previous
//
#include <hip/hip_runtime.h>

typedef _Float16 half8  __attribute__((ext_vector_type(8)));
typedef _Float16 half4v __attribute__((ext_vector_type(4)));
typedef _Float16 half2v __attribute__((ext_vector_type(2)));
typedef float    f32x4  __attribute__((ext_vector_type(4)));

#define N_VOX  262144
#define BATCH  4
#define NBOX   32
#define C3D_   64
#define C2D_   256
#define MIDC   128
#define OUTC   64
#define IH     96
#define IW     312
#define IHW    (IH*IW)          // 29952
#define EPSF   1e-5f

#define MFMA16(a,b,c) __builtin_amdgcn_mfma_f32_16x16x32_f16(a,b,c,0,0,0)

// ---------------------------------------------------------------------------
// prep_all: (a) BN-folded fp16 weights + fp32 biases, (b) per-voxel w3d.
// grid = 1024 x 256 (1 thread per voxel for w3d; low ids also do weights).
// ---------------------------------------------------------------------------
__global__ __launch_bounds__(256) void prep_all(
    const int*   __restrict__ coords,  // [N][4]
    const float* __restrict__ gtb,     // [B][32][7]
    const int*   __restrict__ gtc,     // [B][32]
    const float* __restrict__ w_vt, const float* __restrict__ g_vt,
    const float* __restrict__ v_vt, const float* __restrict__ b_vt,
    const float* __restrict__ be_vt, const float* __restrict__ m_vt,
    const float* __restrict__ w_it, const float* __restrict__ g_it,
    const float* __restrict__ v_it, const float* __restrict__ b_it,
    const float* __restrict__ be_it, const float* __restrict__ m_it,
    const float* __restrict__ w_f, const float* __restrict__ g_f,
    const float* __restrict__ v_f, const float* __restrict__ b_f,
    const float* __restrict__ be_f, const float* __restrict__ m_f,
    _Float16* __restrict__ w_vt_s, _Float16* __restrict__ w_it_s,
    _Float16* __restrict__ w_f1_s, _Float16* __restrict__ w_f2_s,
    float* __restrict__ sb_vt, float* __restrict__ sb_it,
    float* __restrict__ sb_f,  float* __restrict__ w3d_buf)
{
    __shared__ float s_box[BATCH*NBOX*7];
    __shared__ int   s_cls[BATCH*NBOX];
    const int tid = threadIdx.x;
    for (int i = tid; i < BATCH*NBOX*7; i += 256) s_box[i] = gtb[i];
    for (int i = tid; i < BATCH*NBOX;   i += 256) s_cls[i] = gtc[i];
    __syncthreads();

    const int v = blockIdx.x * 256 + tid;

    // ---- per-voxel class weight w3d ----
    {
        const int4 cc = ((const int4*)coords)[v];
        const int vb = cc.x;
        const float crx = cc.w * 0.05f;
        const float cry = cc.z * 0.05f - 40.0f;
        const float crz = cc.y * 0.1f  - 3.0f;
        const float* gb = s_box + vb*(NBOX*7);
        int lastm = -1;
        #pragma unroll 8
        for (int m = 0; m < NBOX; ++m) {
            float dx = gb[m*7+3];
            bool in = (fabsf(crx - gb[m*7+0]) < dx * 0.5f) &&
                      (fabsf(cry - gb[m*7+1]) < gb[m*7+4] * 0.5f) &&
                      (fabsf(crz - gb[m*7+2]) < gb[m*7+5] * 0.5f) &&
                      (dx > 0.f);
            if (in) lastm = m;
        }
        float w3 = 0.8f;
        if (lastm >= 0) {
            int cls = s_cls[vb*NBOX + lastm];
            w3 = (cls == 0) ? 0.85f : ((cls == 1) ? 0.95f : 0.6f);
        }
        w3d_buf[v] = w3;
    }

    // ---- BN-folded weights ----
    if (v < MIDC*C3D_) {
        int o = v >> 6;
        float sa = g_vt[o] * rsqrtf(v_vt[o] + EPSF);
        w_vt_s[v] = (_Float16)(w_vt[v] * sa);
    }
    if (v < MIDC*C2D_) {
        int o = v >> 8;
        float sa = g_it[o] * rsqrtf(v_it[o] + EPSF);
        w_it_s[v] = (_Float16)(w_it[v] * sa);
    }
    if (v < OUTC*C2D_) {
        int o = v >> 8, k = v & 255;
        float sa = g_f[o] * rsqrtf(v_f[o] + EPSF);
        float val = w_f[v] * sa;
        if (k < 128) w_f1_s[o*128 + k]       = (_Float16)val;
        else         w_f2_s[o*128 + (k-128)] = (_Float16)val;
    }
    if (v < MIDC) {
        float sa = g_vt[v] * rsqrtf(v_vt[v] + EPSF);
        sb_vt[v] = (b_vt[v] - m_vt[v]) * sa + be_vt[v];
        float si = g_it[v] * rsqrtf(v_it[v] + EPSF);
        sb_it[v] = (b_it[v] - m_it[v]) * si + be_it[v];
    }
    if (v < OUTC) {
        float sa = g_f[v] * rsqrtf(v_f[v] + EPSF);
        sb_f[v] = (b_f[v] - m_f[v]) * sa + be_f[v];
    }
}

// ---------------------------------------------------------------------------
// Kernel A: T = relu(img @ w_it_s^T + sb_it), J' = T @ w_f2_s^T
// -> J[b][p][64] fp16.  (HBM-read-bound.)
// ---------------------------------------------------------------------------
__global__ __launch_bounds__(256, 4) void img_transform(
    const float* __restrict__ img,        // [B][256][H*W]
    const _Float16* __restrict__ w_it_s,  // [128][256] fp16, BN-folded
    const _Float16* __restrict__ w_f2_s,  // [64][128] fp16, BN-folded
    const float* __restrict__ sb_it,      // [128]
    _Float16* __restrict__ Jout)          // [B][H*W][64] fp16
{
    __shared__ __align__(16) _Float16 s_mem[64*136];

    const int p0   = blockIdx.x * 64;
    const int b    = blockIdx.y;
    const int tid  = threadIdx.x;
    const int lane = tid & 63;
    const int wv   = tid >> 6;
    const int r    = lane & 15;
    const int kh   = lane >> 4;

    f32x4 acc[4][2] = {};

    const int p  = tid & 63;
    const int cb = (tid >> 6) * 2;

    const float sbit0 = sb_it[wv*32 + r];
    const float sbit1 = sb_it[wv*32 + 16 + r];

    for (int kc = 0; kc < 4; ++kc) {
        #pragma unroll
        for (int i = 0; i < 8; ++i) {
            int c = cb + i*8;
            float x0 = img[(size_t)(b*C2D_ + kc*64 + c    )*IHW + p0 + p];
            float x1 = img[(size_t)(b*C2D_ + kc*64 + c + 1)*IHW + p0 + p];
            half2v h; h[0] = (_Float16)x0; h[1] = (_Float16)x1;
            *(half2v*)&s_mem[p*72 + c] = h;
        }
        half8 bw[2][2];
        #pragma unroll
        for (int nt = 0; nt < 2; ++nt)
            #pragma unroll
            for (int ks = 0; ks < 2; ++ks) {
                int o = wv*32 + nt*16 + r;
                bw[nt][ks] = *(const half8*)&w_it_s[o*C2D_ + kc*64 + ks*32 + kh*8];
            }
        __syncthreads();
        #pragma unroll
        for (int mt = 0; mt < 4; ++mt)
            #pragma unroll
            for (int ks = 0; ks < 2; ++ks) {
                half8 af = *(const half8*)&s_mem[(mt*16 + r)*72 + ks*32 + kh*8];
                acc[mt][0] = MFMA16(af, bw[0][ks], acc[mt][0]);
                acc[mt][1] = MFMA16(af, bw[1][ks], acc[mt][1]);
            }
        __syncthreads();
    }

    #pragma unroll
    for (int nt = 0; nt < 2; ++nt) {
        int o = wv*32 + nt*16 + r;
        float sb = nt ? sbit1 : sbit0;
        #pragma unroll
        for (int mt = 0; mt < 4; ++mt)
            #pragma unroll
            for (int rr = 0; rr < 4; ++rr) {
                int p2 = mt*16 + kh*4 + rr;
                s_mem[p2*136 + o] = (_Float16)fmaxf(acc[mt][nt][rr] + sb, 0.f);
            }
    }
    __syncthreads();

    {
        const int o2 = wv*16 + r;
        half8 bf2[4];
        #pragma unroll
        for (int ks = 0; ks < 4; ++ks)
            bf2[ks] = *(const half8*)&w_f2_s[o2*128 + ks*32 + kh*8];
        #pragma unroll
        for (int mt = 0; mt < 4; ++mt) {
            f32x4 a2 = {0.f,0.f,0.f,0.f};
            #pragma unroll
            for (int ks = 0; ks < 4; ++ks) {
                half8 af = *(const half8*)&s_mem[(mt*16 + r)*136 + ks*32 + kh*8];
                a2 = MFMA16(af, bf2[ks], a2);
            }
            #pragma unroll
            for (int rr = 0; rr < 4; ++rr) {
                int p2 = mt*16 + kh*4 + rr;
                Jout[(size_t)(b*IHW + p0 + p2)*OUTC + o2] = (_Float16)a2[rr];
            }
        }
    }
}

// ---------------------------------------------------------------------------
// Kernel B (round-5 structure): 64 voxels/block, 4 blocks/CU.
// meta precomputed w3d; J-gather issued AFTER bar1 so it hides under MFMA.
// ---------------------------------------------------------------------------
__global__ __launch_bounds__(256, 4) void voxel_fuse(
    const float* __restrict__ vf,         // [N][64]
    const int*   __restrict__ coords,     // [N][4]
    const _Float16* __restrict__ w_vt_s,  // [128][64] BN-folded
    const float* __restrict__ sb_vt,      // [128]
    const _Float16* __restrict__ Jimg,    // [B][H*W][64]
    const _Float16* __restrict__ w_f1_s,  // [64][128] BN-folded
    const float* __restrict__ sb_f,       // [64]
    const float* __restrict__ w3d_buf,    // [N]
    float* __restrict__ out)              // [N][64]
{
    __shared__ __align__(16) _Float16 s_vf[64*72];      // [v][k] pitch 72
    __shared__ __align__(16) _Float16 s_fused[64*136];  // [v][o] pitch 136
    __shared__ __align__(16) _Float16 s_j[64*72];       // [v][o] pitch 72
    __shared__ float s_w3d[64];

    const int tid  = threadIdx.x;
    const int lane = tid & 63;
    const int wv   = tid >> 6;
    const int v0   = blockIdx.x * 64;
    const int r    = lane & 15;
    const int kh   = lane >> 4;
    const int vsv  = tid >> 2;
    const int q_   = tid & 3;

    // ---- issue vf + w3d + coords loads ----
    float4 vfr[4];
    {
        const float4* src = (const float4*)(vf + (size_t)(v0 + vsv)*C3D_ + q_*16);
        #pragma unroll
        for (int i = 0; i < 4; ++i) vfr[i] = src[i];
    }
    const float w3 = w3d_buf[v0 + vsv];
    const int4 cc = ((const int4*)coords)[v0 + vsv];

    // ---- per-thread gather meta ----
    int ga[4]; float gw[4];
    {
        const int vb = cc.x;
        const float crx = cc.w * 0.05f;
        const float cry = cc.z * 0.05f - 40.0f;
        const float px = (crx + 0.025f) * 10.f + 156.f;
        const float py = (cry + 0.025f) * 10.f + 48.f;
        const float nx = fminf(fmaxf(px / 312.f * 2.f - 1.f, -1.f), 1.f);
        const float ny = fminf(fmaxf(py / 96.f  * 2.f - 1.f, -1.f), 1.f);
        const float fx = ((nx + 1.f) * 312.f - 1.f) * 0.5f;
        const float fy = ((ny + 1.f) * 96.f  - 1.f) * 0.5f;
        const float x0f = floorf(fx), y0f = floorf(fy);
        const float wx1 = fx - x0f, wy1 = fy - y0f;
        const int x0 = (int)x0f, y0 = (int)y0f;
        #pragma unroll
        for (int c = 0; c < 4; ++c) {
            int xi = x0 + (c & 1), yi = y0 + (c >> 1);
            bool valid = (xi >= 0) && (xi < IW) && (yi >= 0) && (yi < IH);
            int xc = min(max(xi, 0), IW - 1);
            int yc = min(max(yi, 0), IH - 1);
            ga[c] = ((vb*IH + yc)*IW + xc) * OUTC;
            float wx = (c & 1) ? wx1 : 1.f - wx1;
            float wy = (c >> 1) ? wy1 : 1.f - wy1;
            gw[c] = valid ? wx * wy : 0.f;
        }
    }

    // ---- weight fragments + biases (L2-hot) ----
    half8 bvt[2][2];
    float sbvt[2];
    #pragma unroll
    for (int nt = 0; nt < 2; ++nt) {
        int o = (2*wv + nt)*16 + r;
        #pragma unroll
        for (int ks = 0; ks < 2; ++ks)
            bvt[nt][ks] = *(const half8*)&w_vt_s[o*C3D_ + ks*32 + kh*8];
        sbvt[nt] = sb_vt[o];
    }
    const int of = wv*16 + r;
    half8 bf1[4];
    #pragma unroll
    for (int ks = 0; ks < 4; ++ks)
        bf1[ks] = *(const half8*)&w_f1_s[of*128 + ks*32 + kh*8];
    const float sbf = sb_f[of];

    // ---- stage vf -> fp16 LDS; publish w3d ----
    #pragma unroll
    for (int i = 0; i < 4; ++i) {
        float4 x = vfr[i];
        half4v h;
        h[0] = (_Float16)x.x; h[1] = (_Float16)x.y;
        h[2] = (_Float16)x.z; h[3] = (_Float16)x.w;
        *(half4v*)&s_vf[vsv*72 + q_*16 + i*4] = h;
    }
    if (q_ == 0) s_w3d[vsv] = w3;
    __syncthreads();

    // ---- issue J-gather AFTER bar1: hides under phase-1a MFMA ----
    half8 jreg[4][2];
    #pragma unroll
    for (int c = 0; c < 4; ++c)
        #pragma unroll
        for (int h = 0; h < 2; ++h)
            jreg[c][h] = *(const half8*)&Jimg[ga[c] + (h*4 + q_)*8];

    // ---- phase 1a: vt = relu(vf @ w_vt_s^T + sb) * w3d -> s_fused ----
    #pragma unroll
    for (int mt = 0; mt < 4; ++mt) {
        f32x4 a0 = {0.f,0.f,0.f,0.f}, a1 = {0.f,0.f,0.f,0.f};
        #pragma unroll
        for (int ks = 0; ks < 2; ++ks) {
            half8 af = *(const half8*)&s_vf[(mt*16 + r)*72 + ks*32 + kh*8];
            a0 = MFMA16(af, bvt[0][ks], a0);
            a1 = MFMA16(af, bvt[1][ks], a1);
        }
        #pragma unroll
        for (int rr = 0; rr < 4; ++rr) {
            int v = mt*16 + kh*4 + rr;
            float w3v = s_w3d[v];
            s_fused[v*136 + (2*wv+0)*16 + r] =
                (_Float16)(fmaxf(a0[rr] + sbvt[0], 0.f) * w3v);
            s_fused[v*136 + (2*wv+1)*16 + r] =
                (_Float16)(fmaxf(a1[rr] + sbvt[1], 0.f) * w3v);
        }
    }

    // ---- gather combine: (1-w3d)*sum_c gw[c]*J_c -> s_j ----
    {
        float invw = 1.f - w3;
        #pragma unroll
        for (int h = 0; h < 2; ++h) {
            half8 res;
            #pragma unroll
            for (int i = 0; i < 8; ++i) {
                float s = gw[0]*(float)jreg[0][h][i] + gw[1]*(float)jreg[1][h][i]
                        + gw[2]*(float)jreg[2][h][i] + gw[3]*(float)jreg[3][h][i];
                res[i] = (_Float16)(s * invw);
            }
            *(half8*)&s_j[vsv*72 + (h*4 + q_)*8] = res;
        }
    }
    __syncthreads();

    // ---- phase 2: out = relu(fused @ w_f1_s^T + j + sb_f) ----
    #pragma unroll
    for (int mt = 0; mt < 4; ++mt) {
        f32x4 acc = {0.f,0.f,0.f,0.f};
        #pragma unroll
        for (int ks = 0; ks < 4; ++ks) {
            half8 af = *(const half8*)&s_fused[(mt*16 + r)*136 + ks*32 + kh*8];
            acc = MFMA16(af, bf1[ks], acc);
        }
        #pragma unroll
        for (int rr = 0; rr < 4; ++rr) {
            int v = mt*16 + kh*4 + rr;
            float jv = (float)s_j[v*72 + of];
            out[(size_t)(v0 + v)*OUTC + of] = fmaxf(acc[rr] + jv + sbf, 0.f);
        }
    }
}

// ---------------------------------------------------------------------------
extern "C" void kernel_launch(void* const* d_in, const int* in_sizes, int n_in,
                              void* d_out, int out_size, void* d_ws, size_t ws_size,
                              hipStream_t stream)
{
    const float* vf    = (const float*)d_in[0];
    const int*   vc    = (const int*)  d_in[1];
    const float* img   = (const float*)d_in[2];
    const float* gtb   = (const float*)d_in[3];
    const int*   gtc   = (const int*)  d_in[4];
    const float* w_vt  = (const float*)d_in[5];
    const float* b_vt  = (const float*)d_in[6];
    const float* g_vt  = (const float*)d_in[7];
    const float* be_vt = (const float*)d_in[8];
    const float* m_vt  = (const float*)d_in[9];
    const float* v_vt  = (const float*)d_in[10];
    const float* w_it  = (const float*)d_in[11];
    const float* b_it  = (const float*)d_in[12];
    const float* g_it  = (const float*)d_in[13];
    const float* be_it = (const float*)d_in[14];
    const float* m_it  = (const float*)d_in[15];
    const float* v_it  = (const float*)d_in[16];
    const float* w_f   = (const float*)d_in[17];
    const float* b_f   = (const float*)d_in[18];
    const float* g_f   = (const float*)d_in[19];
    const float* be_f  = (const float*)d_in[20];
    const float* m_f   = (const float*)d_in[21];
    const float* v_f   = (const float*)d_in[22];

    _Float16* ws_h   = (_Float16*)d_ws;
    _Float16* Jbuf   = ws_h;                              // B*IHW*64
    _Float16* w_vt_s = ws_h + (size_t)BATCH*IHW*OUTC;     // 8192
    _Float16* w_it_s = w_vt_s + MIDC*C3D_;                // 32768
    _Float16* w_f1_s = w_it_s + MIDC*C2D_;                // 8192
    _Float16* w_f2_s = w_f1_s + OUTC*128;                 // 8192
    float*    fbase  = (float*)(w_f2_s + OUTC*128);
    float* sb_vt   = fbase;                               // 128
    float* sb_it   = sb_vt + MIDC;                        // 128
    float* sb_f    = sb_it + MIDC;                        // 64
    float* w3d_buf = sb_f + OUTC;                         // N_VOX
    float* outp = (float*)d_out;

    prep_all<<<N_VOX/256, 256, 0, stream>>>(
        vc, gtb, gtc,
        w_vt, g_vt, v_vt, b_vt, be_vt, m_vt,
        w_it, g_it, v_it, b_it, be_it, m_it,
        w_f,  g_f,  v_f,  b_f,  be_f,  m_f,
        w_vt_s, w_it_s, w_f1_s, w_f2_s,
        sb_vt, sb_it, sb_f, w3d_buf);

    img_transform<<<dim3(IHW/64, BATCH), 256, 0, stream>>>(
        img, w_it_s, w_f2_s, sb_it, Jbuf);

    voxel_fuse<<<N_VOX/64, 256, 0, stream>>>(
        vf, vc, w_vt_s, sb_vt, Jbuf, w_f1_s, sb_f, w3d_buf, outp);
}